// Round 1
// baseline (2873.220 us; speedup 1.0000x reference)
//
#include <hip/hip_runtime.h>
#include <math.h>

#define NN 100000
#define BB 8
#define SIGMA_C 162.13039087945623f
#define MU_C 117.41975505778706f

__device__ __forceinline__ float fast_tanh(float v) {
    // tanh(v) = 1 - 2/(1 + e^{2v});  e^{2v} = exp2(v * 2/ln2)
#if __has_builtin(__builtin_amdgcn_exp2f) && __has_builtin(__builtin_amdgcn_rcpf)
    float e = __builtin_amdgcn_exp2f(v * 2.8853900817779268f);
    return 1.0f - 2.0f * __builtin_amdgcn_rcpf(e + 1.0f);
#else
    return tanhf(v);
#endif
}

__global__ void init_out_kernel(float* out) {
    if (threadIdx.x < BB) out[threadIdx.x] = MU_C;
}

__global__ __launch_bounds__(256) void mol_gnn_kernel(
    const float* __restrict__ features,
    const float* __restrict__ nb_connect,
    const float* __restrict__ weights,
    const float* __restrict__ w_scalar,
    const float* __restrict__ w0, const float* __restrict__ b0,
    const float* __restrict__ w1, const float* __restrict__ b1,
    const float* __restrict__ w2, const float* __restrict__ b2,
    const float* __restrict__ w3, const float* __restrict__ b3,
    const float* __restrict__ w4, const float* __restrict__ b4,
    const float* __restrict__ wf, const float* __restrict__ bf,
    float* out)
{
    __shared__ float red[BB];
    if (threadIdx.x < BB) red[threadIdx.x] = 0.0f;
    __syncthreads();

    const int tid = blockIdx.x * blockDim.x + threadIdx.x;  // grid == 800000 exactly
    const int b = tid / NN;
    const int n = tid - b * NN;

    // ---- message-pass coefficients (per node) ----
    const float wv = w_scalar[0];
    float nbc[6];
    #pragma unroll
    for (int i = 0; i < 6; ++i) nbc[i] = nb_connect[n * 6 + i];
    const float nb0 = nbc[0] + nbc[1] + nbc[2];
    const float nb1 = nbc[3] + nbc[4] + nbc[5];
    const float eps = 1e-5f;
    const float nb0s = (nb0 < eps) ? eps : nb0;
    const float nb1s = (nb1 < eps) ? eps : nb1;
    const float h0 = (nb0 > 0.0f) ? 1.0f : 0.0f;
    const float h1 = (nb1 > 0.0f) ? 1.0f : 0.0f;
    float c[7];
    c[0] = 1.0f - h0 * wv - h1 * wv;
    const float i0 = wv / nb0s;
    const float i1 = wv / nb1s;
    c[1] = nbc[0] * i0; c[2] = nbc[1] * i0; c[3] = nbc[2] * i0;
    c[4] = nbc[3] * i1; c[5] = nbc[4] * i1; c[6] = nbc[5] * i1;

    const float* frow = features + ((size_t)b * NN + (size_t)n) * 280;

    float acc[20];
    #pragma unroll
    for (int j = 0; j < 20; ++j) acc[j] = 0.0f;

    // ---- fc0 MLP per s-row, message-pass fused into acc ----
    for (int s = 0; s < 7; ++s) {
        float x[40];
        const float4* xv = (const float4*)(frow + s * 40);
        #pragma unroll
        for (int i = 0; i < 10; ++i) {
            float4 v = xv[i];
            x[4*i+0] = v.x; x[4*i+1] = v.y; x[4*i+2] = v.z; x[4*i+3] = v.w;
        }
        float y[40];
        #pragma unroll
        for (int j = 0; j < 40; ++j) {
            float t = b0[j];
            #pragma unroll
            for (int k = 0; k < 40; ++k) t += w0[j*40+k] * x[k];
            y[j] = fast_tanh(t);
        }
        float z[20];
        #pragma unroll
        for (int j = 0; j < 20; ++j) {
            float t = b1[j];
            #pragma unroll
            for (int k = 0; k < 40; ++k) t += w1[j*40+k] * y[k];
            z[j] = fast_tanh(t);
        }
        const float cs = c[s];
        #pragma unroll
        for (int j = 0; j < 20; ++j) {
            float t = b2[j];
            #pragma unroll
            for (int k = 0; k < 20; ++k) t += w2[j*20+k] * z[k];
            acc[j] += cs * fast_tanh(t);
        }
    }

    // ---- fc1 + final head ----
    float t1[20];
    #pragma unroll
    for (int j = 0; j < 20; ++j) {
        float t = b3[j];
        #pragma unroll
        for (int k = 0; k < 20; ++k) t += w3[j*20+k] * acc[k];
        t1[j] = fast_tanh(t);
    }
    float e = bf[0];
    #pragma unroll
    for (int j = 0; j < 10; ++j) {
        float t = b4[j];
        #pragma unroll
        for (int k = 0; k < 20; ++k) t += w4[j*20+k] * t1[k];
        e += wf[j] * fast_tanh(t);
    }

    const float contrib = weights[n] * e;

    // ---- per-block reduction, then one global atomic per b present ----
    atomicAdd(&red[b], contrib);
    __syncthreads();
    if (threadIdx.x < BB) {
        float v = red[threadIdx.x];
        if (v != 0.0f) atomicAdd(out + threadIdx.x, v * SIGMA_C);
    }
}

extern "C" void kernel_launch(void* const* d_in, const int* in_sizes, int n_in,
                              void* d_out, int out_size, void* d_ws, size_t ws_size,
                              hipStream_t stream) {
    const float* features   = (const float*)d_in[0];
    const float* nb_connect = (const float*)d_in[1];
    const float* weights    = (const float*)d_in[2];
    const float* w_scalar   = (const float*)d_in[3];
    const float* w0 = (const float*)d_in[4];  const float* b0 = (const float*)d_in[5];
    const float* w1 = (const float*)d_in[6];  const float* b1 = (const float*)d_in[7];
    const float* w2 = (const float*)d_in[8];  const float* b2 = (const float*)d_in[9];
    const float* w3 = (const float*)d_in[10]; const float* b3 = (const float*)d_in[11];
    const float* w4 = (const float*)d_in[12]; const float* b4 = (const float*)d_in[13];
    const float* wf = (const float*)d_in[14]; const float* bf = (const float*)d_in[15];
    float* out = (float*)d_out;

    hipLaunchKernelGGL(init_out_kernel, dim3(1), dim3(64), 0, stream, out);

    const int total = BB * NN;             // 800000
    const int block = 256;
    const int grid = (total + block - 1) / block;  // 3125
    hipLaunchKernelGGL(mol_gnn_kernel, dim3(grid), dim3(block), 0, stream,
                       features, nb_connect, weights, w_scalar,
                       w0, b0, w1, b1, w2, b2, w3, b3, w4, b4, wf, bf, out);
}